// Round 2
// baseline (839.521 us; speedup 1.0000x reference)
//
#include <hip/hip_runtime.h>
#include <hip/hip_bf16.h>

// ---------------------------------------------------------------------------
// dist = (1/(N*P*M)) * sum_{n,m,p} || src[p] - pe[n,m] + 1e-6 ||_2
// P=50 (pad 64), M=197, N=1024 (N*M = 201728 = 1576*128), D=768
//
// ||a'-b||^2 = ||a'||^2 + ||b||^2 - 2 a'.b, a' = src + eps. Cross term via
// bf16 MFMA 16x16x32.
//
// R5 (= R4 with literal chunk indices so global_load_lds offsets are ICEs):
//  - barrier-free wave-private K-loop; wave's own 2x4KB LDS double-buffer.
//  - A-fragments double-buffered in registers (afA/afB), prefetched one
//    chunk ahead together with the LDS stage; single in-wave
//    `s_waitcnt vmcnt(12)` retires {stage(it), af(it)} and keeps
//    {stage(it+1), af(it+1)} = 12 loads in flight (was 4).
//  - f32->bf16 via v_cvt_pk (native RNE) instead of manual bit-trick.
//  - stage addresses precomputed; per-chunk advance rides in the
//    global_load_lds immediate offset (literal IT => constant).
// ws: [0) partials f32[1576]; [8192) na f32[64]; [16384) A bf16[64][768]
// ---------------------------------------------------------------------------

typedef __attribute__((ext_vector_type(8))) short bf16x8;
typedef __attribute__((ext_vector_type(4))) float f32x4;

#define D_DIM 768
#define NM_TOTAL 201728
#define COLS_PER_WG 128
#define NUM_WG (NM_TOTAL / COLS_PER_WG)   // 1576
#define KC 64                              // fp32 k-elements per col per chunk
#define NCHUNK (D_DIM / KC)                // 12
#define CPW 16                             // cols per wave

__device__ __forceinline__ unsigned short f2bf(float f) {
  unsigned int u = __float_as_uint(f);
  u += 0x7FFFu + ((u >> 16) & 1u);
  return (unsigned short)(u >> 16);
}

__global__ void prep_kernel(const float* __restrict__ src,
                            short* __restrict__ aW,
                            float* __restrict__ na) {
  const int r = blockIdx.x;        // 0..63, one wave per row
  const int lane = threadIdx.x;    // 0..63
  float sq = 0.f;
#pragma unroll
  for (int j = 0; j < 12; ++j) {
    const int c = lane + j * 64;
    float v = 0.f;
    if (r < 50) v = src[r * D_DIM + c] + 1e-6f;
    sq += v * v;
    aW[r * D_DIM + c] = (short)f2bf(v);
  }
#pragma unroll
  for (int m = 32; m >= 1; m >>= 1) sq += __shfl_xor(sq, m);
  if (lane == 0) na[r] = sq;
}

// One chunk. IT and CUR must be LITERAL integers (global_load_lds offset is
// an ICE). Prefetch {stage, A-frags} for chunk IT+1, wait, MFMA chunk IT.
#define CHUNK(IT, CUR, AFC, AFN)                                              \
  {                                                                           \
    if ((IT) + 1 < NCHUNK) {                                                  \
      _Pragma("unroll")                                                       \
      for (int r = 0; r < 4; ++r) {                                           \
        __builtin_amdgcn_global_load_lds(                                     \
            (const __attribute__((address_space(1))) void*)gp[r],             \
            (__attribute__((address_space(3))) void*)                         \
                &buf[wave][(CUR) ^ 1][(r * 4) * KC],                          \
            16, ((IT) + 1) * KC * 4, 0);                                      \
      }                                                                       \
      _Pragma("unroll")                                                       \
      for (int s = 0; s < 2; ++s)                                             \
        _Pragma("unroll")                                                     \
        for (int t = 0; t < 4; ++t)                                           \
          AFN[s][t] = *(const bf16x8*)(aW_lane + (size_t)(t * 16) * D_DIM +   \
                                       ((IT) + 1) * KC + s * 32);             \
      asm volatile("s_waitcnt vmcnt(12)" ::: "memory");                       \
    } else {                                                                  \
      asm volatile("s_waitcnt vmcnt(0)" ::: "memory");                        \
    }                                                                         \
    const float* bufc = buf[wave][CUR];                                       \
    _Pragma("unroll")                                                         \
    for (int s = 0; s < 2; ++s) {                                             \
      const int P0 = s * 8 + quad * 2;                                        \
      const f32x4 u0 = *(const f32x4*)&bufc[l16 * KC + ((P0 ^ l16) << 2)];    \
      const f32x4 u1 =                                                        \
          *(const f32x4*)&bufc[l16 * KC + (((P0 + 1) ^ l16) << 2)];           \
      nb = fmaf(u0.x, u0.x, nb); nb = fmaf(u0.y, u0.y, nb);                   \
      nb = fmaf(u0.z, u0.z, nb); nb = fmaf(u0.w, u0.w, nb);                   \
      nb = fmaf(u1.x, u1.x, nb); nb = fmaf(u1.y, u1.y, nb);                   \
      nb = fmaf(u1.z, u1.z, nb); nb = fmaf(u1.w, u1.w, nb);                   \
      union { bf16x8 v; __hip_bfloat162 h[4]; } b;                            \
      b.h[0] = __float22bfloat162_rn(make_float2(u0.x, u0.y));                \
      b.h[1] = __float22bfloat162_rn(make_float2(u0.z, u0.w));                \
      b.h[2] = __float22bfloat162_rn(make_float2(u1.x, u1.y));                \
      b.h[3] = __float22bfloat162_rn(make_float2(u1.z, u1.w));                \
      acc0 = __builtin_amdgcn_mfma_f32_16x16x32_bf16(AFC[s][0], b.v, acc0, 0, 0, 0); \
      acc1 = __builtin_amdgcn_mfma_f32_16x16x32_bf16(AFC[s][1], b.v, acc1, 0, 0, 0); \
      acc2 = __builtin_amdgcn_mfma_f32_16x16x32_bf16(AFC[s][2], b.v, acc2, 0, 0, 0); \
      acc3 = __builtin_amdgcn_mfma_f32_16x16x32_bf16(AFC[s][3], b.v, acc3, 0, 0, 0); \
    }                                                                         \
  }

__global__ __launch_bounds__(512, 4) void dist_kernel(
    const float* __restrict__ pe,
    const short* __restrict__ aW,
    const float* __restrict__ na,
    float* __restrict__ partials) {
  // 8 waves x 2 buffers x (16 cols x 64 k fp32 = 4 KB) = 64 KB static LDS
  __shared__ __attribute__((aligned(16))) float buf[8][2][CPW * KC];

  const int tid  = threadIdx.x;
  const int wave = tid >> 6;
  const int lane = tid & 63;
  const int quad = lane >> 4;
  const int l16  = lane & 15;

  const int colbase = blockIdx.x * COLS_PER_WG + wave * CPW;

  // staging: round r fills local cols [r*4, r*4+4): lane L -> col r*4+(L>>4),
  // 16-B chunk position L&15, XOR-swizzled source so reads are bank-uniform.
  const int s_sub = lane >> 4;
  const int cpos  = lane & 15;

  // per-lane loop-invariant bases
  const float* gp[4];
#pragma unroll
  for (int r = 0; r < 4; ++r) {
    const int cl = r * 4 + s_sub;
    gp[r] = pe + (size_t)(colbase + cl) * D_DIM + ((cpos ^ cl) << 2);
  }
  const short* aW_lane = aW + (size_t)l16 * D_DIM + quad * 8;

  f32x4 acc0 = {0.f, 0.f, 0.f, 0.f};
  f32x4 acc1 = {0.f, 0.f, 0.f, 0.f};
  f32x4 acc2 = {0.f, 0.f, 0.f, 0.f};
  f32x4 acc3 = {0.f, 0.f, 0.f, 0.f};
  float nb = 0.f;

  bf16x8 afA[2][4], afB[2][4];

  // ---- prologue: stage chunk 0 into buf[wave][0]; A-frags chunk 0 -> afA ----
#pragma unroll
  for (int r = 0; r < 4; ++r) {
    __builtin_amdgcn_global_load_lds(
        (const __attribute__((address_space(1))) void*)gp[r],
        (__attribute__((address_space(3))) void*)&buf[wave][0][(r * 4) * KC],
        16, 0, 0);
  }
#pragma unroll
  for (int s = 0; s < 2; ++s)
#pragma unroll
    for (int t = 0; t < 4; ++t)
      afA[s][t] = *(const bf16x8*)(aW_lane + (size_t)(t * 16) * D_DIM + s * 32);

  // ---- 12 chunks, literal indices (ICE requirement) ----
  CHUNK(0,  0, afA, afB);
  CHUNK(1,  1, afB, afA);
  CHUNK(2,  0, afA, afB);
  CHUNK(3,  1, afB, afA);
  CHUNK(4,  0, afA, afB);
  CHUNK(5,  1, afB, afA);
  CHUNK(6,  0, afA, afB);
  CHUNK(7,  1, afB, afA);
  CHUNK(8,  0, afA, afB);
  CHUNK(9,  1, afB, afA);
  CHUNK(10, 0, afA, afB);
  CHUNK(11, 1, afB, afA);

  // nb holds this lane's quad-partial of ||b_col||^2; sum the 4 quads
  nb += __shfl_xor(nb, 16);
  nb += __shfl_xor(nb, 32);

  // epilogue: C[p][col] at col=lane&15, row p_local = quad*4 + reg
  float s = 0.f;
  {
    f32x4 accs[4] = {acc0, acc1, acc2, acc3};
#pragma unroll
    for (int t = 0; t < 4; ++t) {
#pragma unroll
      for (int r = 0; r < 4; ++r) {
        const int p = t * 16 + quad * 4 + r;
        if (p < 50) {
          const float c = accs[t][r];
          const float d2 = fmaxf(na[p] + nb - 2.f * c, 0.f);
          s += sqrtf(d2);
        }
      }
    }
  }

#pragma unroll
  for (int m = 32; m >= 1; m >>= 1) s += __shfl_xor(s, m);

  // cross-wave reduction: waves are desynced, so barrier before reusing buf
  __syncthreads();
  float* wsum = (float*)buf;
  if (lane == 0) wsum[wave] = s;
  __syncthreads();
  if (tid == 0) {
    float t = 0.f;
#pragma unroll
    for (int i = 0; i < 8; ++i) t += wsum[i];
    partials[blockIdx.x] = t;
  }
}

#undef CHUNK

__global__ void finalize_kernel(const float* __restrict__ partials,
                                float* __restrict__ out) {
  __shared__ float red[256];
  float s = 0.f;
  for (int i = threadIdx.x; i < NUM_WG; i += 256) s += partials[i];
  red[threadIdx.x] = s;
  __syncthreads();
  for (int step = 128; step >= 1; step >>= 1) {
    if (threadIdx.x < step) red[threadIdx.x] += red[threadIdx.x + step];
    __syncthreads();
  }
  // mean over P*M = 9850, then / N = 1024  ->  1/10086400
  if (threadIdx.x == 0) out[0] = red[0] * (1.0f / 10086400.0f);
}

extern "C" void kernel_launch(void* const* d_in, const int* in_sizes, int n_in,
                              void* d_out, int out_size, void* d_ws, size_t ws_size,
                              hipStream_t stream) {
  const float* src = (const float*)d_in[0];   // [50, 768]
  const float* pe  = (const float*)d_in[1];   // [1024, 197, 768]
  float* out = (float*)d_out;

  char* ws = (char*)d_ws;
  float* partials = (float*)ws;                 // 1576 f32
  float* na       = (float*)(ws + 8192);        // 64 f32
  short* aW       = (short*)(ws + 16384);       // 64*768 bf16

  prep_kernel<<<64, 64, 0, stream>>>(src, aW, na);
  dist_kernel<<<NUM_WG, 512, 0, stream>>>(pe, aW, na, partials);
  finalize_kernel<<<1, 256, 0, stream>>>(partials, out);
}